// Round 3
// baseline (466.705 us; speedup 1.0000x reference)
//
#include <hip/hip_runtime.h>
#include <math.h>

#define EPSF 1e-6f

constexpr int Bn = 2, Cn = 32, Dn = 64, Hn = 64, Wn = 64;
constexpr int HW  = Hn * Wn;          // 4096
constexpr int DHW = Dn * HW;          // 262144
constexpr int NVOX = Bn * DHW;        // 524288

// accum layout in ws:
// 0 hinge_num, 1 hinge_den, 2 warp_num, 3 warp_den,
// 4 l1_nz, 5 l1_yz, 6 l2_nz, 7 l2_yz, 8 nz_den, 9 yz_den,
// 10 cyc1, 11 cyc2, 12 smooth_sum

__device__ inline float sl1(float d) {
    float a = fabsf(d);
    return a < 1.f ? 0.5f * d * d : a - 0.5f;
}

// lane i <- lane i-1, lane 0 -> 0   (sample at x-1; x=0 edge zeroed = ref padding)
__device__ inline float dpp_left(float v) {
    int r = __builtin_amdgcn_update_dpp(0, __float_as_int(v), 0x138 /*wave_shr:1*/,
                                        0xF, 0xF, true);
    return __int_as_float(r);
}
// lane i <- lane i+1, lane 63 -> 0  (sample at x+1; x=63 edge zeroed)
__device__ inline float dpp_right(float v) {
    int r = __builtin_amdgcn_update_dpp(0, __float_as_int(v), 0x130 /*wave_shl:1*/,
                                        0xF, 0xF, true);
    return __int_as_float(r);
}

__device__ inline void warp_setup(float flx, float fly, float flz,
                                  int x, int y, int z,
                                  int* idx, float* wv) {
    float xs = (float)x + flx, ys = (float)y + fly, zs = (float)z + flz;
    float x0 = floorf(xs), y0 = floorf(ys), z0 = floorf(zs);
    float fx = xs - x0, fy = ys - y0, fz = zs - z0;
    int xi = (int)x0, yi = (int)y0, zi = (int)z0;
#pragma unroll
    for (int cz = 0; cz < 2; cz++) {
        float wz = cz ? fz : 1.f - fz;
        int zz = zi + cz;
        bool zv = (zz >= 0) && (zz < Dn);
        int zc = zz < 0 ? 0 : (zz > Dn - 1 ? Dn - 1 : zz);
#pragma unroll
        for (int cy = 0; cy < 2; cy++) {
            float wy = cy ? fy : 1.f - fy;
            int yy2 = yi + cy;
            bool yv = (yy2 >= 0) && (yy2 < Hn);
            int yc = yy2 < 0 ? 0 : (yy2 > Hn - 1 ? Hn - 1 : yy2);
#pragma unroll
            for (int cx = 0; cx < 2; cx++) {
                float wx = cx ? fx : 1.f - fx;
                int xx2 = xi + cx;
                bool xv = (xx2 >= 0) && (xx2 < Wn);
                int xc = xx2 < 0 ? 0 : (xx2 > Wn - 1 ? Wn - 1 : xx2);
                int k = cz * 4 + cy * 2 + cx;
                idx[k] = (zc * Hn + yc) * Wn + xc;
                wv[k] = (zv && yv && xv) ? wz * wy * wx : 0.f;
            }
        }
    }
}

// corr3d(f0,f1) -> relu -> l2norm(axis=1) -> W1/leaky -> W2 -> flow_out
// W1/b1/W2/b2 read directly from global with wave-uniform indices -> s_load.
__global__ __launch_bounds__(256)
void corr_flow_kernel(const float* __restrict__ f0, const float* __restrict__ f1,
                      const float* __restrict__ W1, const float* __restrict__ b1,
                      const float* __restrict__ W2, const float* __restrict__ b2,
                      float* __restrict__ flow_out,
                      const float* __restrict__ flow_g,
                      float* __restrict__ accum, int do_hinge) {
    int tid = threadIdx.x;
    int v = blockIdx.x * 256 + tid;
    int x = v & 63, y = (v >> 6) & 63, z = (v >> 12) & 63, b = v >> 18;

    const size_t cb = (size_t)b * Cn * DHW + (size_t)z * HW + y * Wn + x;
    const float* f0p = f0 + cb;
    const float* f1p = f1 + cb;

    // wave-uniform row validity (y,z constant across a wave)
    bool zv0 = z > 0, zv2 = z < Dn - 1;
    bool yv0 = y > 0, yv2 = y < Hn - 1;
    bool rvalid[9] = { zv0 && yv0, zv0, zv0 && yv2,
                       yv0,        true, yv2,
                       zv2 && yv0, zv2, zv2 && yv2 };
    const int rowoff[9] = { -HW - Wn, -HW, -HW + Wn,
                            -Wn,      0,   Wn,
                            HW - Wn,  HW,  HW + Wn };

    float acc[27];
#pragma unroll
    for (int i = 0; i < 27; i++) acc[i] = 0.f;
    float diff2 = 0.f;

    for (int c = 0; c < Cn; c++) {
        const float* p = f1p + (size_t)c * DHW;
        float a = f0p[(size_t)c * DHW];
        float rowv[9];
#pragma unroll
        for (int r = 0; r < 9; r++)
            rowv[r] = rvalid[r] ? p[rowoff[r]] : 0.f;
        float d = rowv[4] - a;
        diff2 = fmaf(d, d, diff2);
#pragma unroll
        for (int r = 0; r < 9; r++) {
            float c0 = rowv[r];
            float lf = dpp_left(c0);
            float rt = dpp_right(c0);
            acc[r * 3 + 0] = fmaf(a, lf, acc[r * 3 + 0]);
            acc[r * 3 + 1] = fmaf(a, c0, acc[r * 3 + 1]);
            acc[r * 3 + 2] = fmaf(a, rt, acc[r * 3 + 2]);
        }
    }

    // flow head: relu, normalize over 27 (eps OUTSIDE sqrt here)
    float ss = 0.f;
#pragma unroll
    for (int i = 0; i < 27; i++) {
        float r = acc[i] > 0.f ? acc[i] : 0.f;
        acc[i] = r;
        ss = fmaf(r, r, ss);
    }
    float inv = 1.0f / (sqrtf(ss) + EPSF);
#pragma unroll
    for (int i = 0; i < 27; i++) acc[i] *= inv;

    float fl0 = b2[0], fl1 = b2[1], fl2 = b2[2];
    for (int o = 0; o < 64; o++) {
        float h = b1[o];
#pragma unroll
        for (int k = 0; k < 27; k++) h = fmaf(W1[o * 27 + k], acc[k], h);
        h = h > 0.f ? h : 0.01f * h;
        fl0 = fmaf(W2[o], h, fl0);
        fl1 = fmaf(W2[64 + o], h, fl1);
        fl2 = fmaf(W2[128 + o], h, fl2);
    }
    size_t fbase = (size_t)b * 3 * DHW + (size_t)z * HW + y * Wn + x;
    flow_out[fbase] = fl0;
    flow_out[fbase + DHW] = fl1;
    flow_out[fbase + 2 * DHW] = fl2;

    if (do_hinge) {
        float ag = fabsf(flow_g[fbase]) + fabsf(flow_g[fbase + DHW]) + fabsf(flow_g[fbase + 2 * DHW]);
        float hmask = ag > 1.0f ? 1.f : 0.f;
        float hv = 0.2f - sqrtf(diff2 + EPSF);
        hv = hv > 0.f ? hv : 0.f;
        float v0 = hv * hmask, v1 = hmask;
        for (int off = 32; off; off >>= 1) {
            v0 += __shfl_down(v0, off, 64);
            v1 += __shfl_down(v1, off, 64);
        }
        __shared__ float s0[4], s1[4];
        int lane = tid & 63, wid = tid >> 6;
        if (lane == 0) { s0[wid] = v0; s1[wid] = v1; }
        __syncthreads();
        if (tid == 0) {
            atomicAdd(&accum[0], s0[0] + s0[1] + s0[2] + s0[3]);
            atomicAdd(&accum[1], s1[0] + s1[1] + s1[2] + s1[3]);
        }
    }
}

// feature warp loss: 4 channel-groups per voxel (8 channels each) for TLP.
// 64 voxels per block; tid = (cg<<6) | voxel_lane.
__global__ __launch_bounds__(256)
void warp_feat_kernel(const float* __restrict__ feat0, const float* __restrict__ feat1,
                      const float* __restrict__ flowf, float* __restrict__ accum) {
    int tid = threadIdx.x;
    int lane = tid & 63;
    int cg = tid >> 6;
    int v = blockIdx.x * 64 + lane;
    int x = v & 63, y = (v >> 6) & 63, z = (v >> 12) & 63, b = v >> 18;

    size_t sp = (size_t)z * HW + y * Wn + x;
    size_t f3 = (size_t)b * 3 * DHW + sp;

    float ffx = flowf[f3], ffy = flowf[f3 + DHW], ffz = flowf[f3 + 2 * DHW];

    int idxF[8]; float wvF[8];
    warp_setup(ffx, ffy, ffz, x, y, z, idxF, wvF);

    const float* f1b = feat1 + (size_t)b * Cn * DHW + (size_t)(cg * 8) * DHW;
    const float* f0b = feat0 + (size_t)b * Cn * DHW + (size_t)(cg * 8) * DHW + sp;
    float s = 0.f;
#pragma unroll
    for (int c = 0; c < 8; c++) {
        const float* pc = f1b + (size_t)c * DHW;
        float g = 0.f;
#pragma unroll
        for (int k = 0; k < 8; k++) g = fmaf(pc[idxF[k]], wvF[k], g);
        float d = g - f0b[(size_t)c * DHW];
        s = fmaf(d, d, s);
    }

    __shared__ float sred[256];
    sred[tid] = s;
    __syncthreads();
    if (tid < 64) {
        float tot = sred[tid] + sred[tid + 64] + sred[tid + 128] + sred[tid + 192];
        float wsum = 0.f;
#pragma unroll
        for (int k = 0; k < 8; k++) wsum += wvF[k];
        float vm = wsum * wsum;   // valid1*valid0 (both use flow_forw in ref)
        float wn = sqrtf(tot + EPSF) * vm;
        float wd = vm;
        for (int off = 32; off; off >>= 1) {
            wn += __shfl_down(wn, off, 64);
            wd += __shfl_down(wd, off, 64);
        }
        if (tid == 0) {
            atomicAdd(&accum[2], wn);
            atomicAdd(&accum[3], wd);
        }
    }
}

// remaining per-voxel losses: cycle, l1/l2 balanced, smoothness
__global__ __launch_bounds__(256)
void loss_rest_kernel(const float* __restrict__ flowf, const float* __restrict__ flowb,
                      const float* __restrict__ flow_g, const float* __restrict__ mask_g,
                      float* __restrict__ accum) {
    int tid = threadIdx.x;
    int v = blockIdx.x * 256 + tid;
    int x = v & 63, y = (v >> 6) & 63, z = (v >> 12) & 63, b = v >> 18;

    size_t sp = (size_t)z * HW + y * Wn + x;
    size_t f3 = (size_t)b * 3 * DHW + sp;

    float ffx = flowf[f3], ffy = flowf[f3 + DHW], ffz = flowf[f3 + 2 * DHW];
    float fbx = flowb[f3], fby = flowb[f3 + DHW], fbz = flowb[f3 + 2 * DHW];
    float gx = flow_g[f3], gy = flow_g[f3 + DHW], gz = flow_g[f3 + 2 * DHW];
    float mg = mask_g[(size_t)b * DHW + sp];

    // cycle 1: fb_al = backwarp(flow_back, flow_forw)
    int idxF[8]; float wvF[8];
    warp_setup(ffx, ffy, ffz, x, y, z, idxF, wvF);
    const float* fb_b = flowb + (size_t)b * 3 * DHW;
    float fbalx = 0.f, fbaly = 0.f, fbalz = 0.f;
#pragma unroll
    for (int k = 0; k < 8; k++) {
        fbalx = fmaf(fb_b[idxF[k]], wvF[k], fbalx);
        fbaly = fmaf(fb_b[DHW + idxF[k]], wvF[k], fbaly);
        fbalz = fmaf(fb_b[2 * DHW + idxF[k]], wvF[k], fbalz);
    }
    float cyc1 = sl1(ffx + fbalx) + sl1(ffy + fbaly) + sl1(ffz + fbalz);

    // cycle 2: ff_al = backwarp(flow_forw, flow_back)
    int idxB[8]; float wvB[8];
    warp_setup(fbx, fby, fbz, x, y, z, idxB, wvB);
    const float* ff_b = flowf + (size_t)b * 3 * DHW;
    float ffalx = 0.f, ffaly = 0.f, ffalz = 0.f;
#pragma unroll
    for (int k = 0; k < 8; k++) {
        ffalx = fmaf(ff_b[idxB[k]], wvB[k], ffalx);
        ffaly = fmaf(ff_b[DHW + idxB[k]], wvB[k], ffaly);
        ffalz = fmaf(ff_b[2 * DHW + idxB[k]], wvB[k], ffalz);
    }
    float cyc2 = sl1(fbx + ffalx) + sl1(fby + ffaly) + sl1(fbz + ffalz);

    // l1/l2 balanced
    float dx0 = ffx - gx, dy0 = ffy - gy, dz0 = ffz - gz;
    float l1 = (sl1(dx0) + sl1(dy0) + sl1(dz0)) * (1.f / 3.f);
    float l2 = (dx0 * dx0 + dy0 * dy0 + dz0 * dz0) * (1.f / 3.f);
    float ag = fabsf(gx) + fabsf(gy) + fabsf(gz);
    float nz = (ag > 0.01f ? 1.f : 0.f) * mg;
    float yz = (1.f - nz) * mg;

    // smoothness: mean over channels of (2*dx + dy), dz unused (ref quirk)
    float sf = 0.f, sb2v = 0.f;
#pragma unroll
    for (int j = 0; j < 3; j++) {
        const float* pf = flowf + f3 + (size_t)j * DHW;
        float c0 = pf[0];
        float ddx = (x < Wn - 1) ? fabsf(pf[1] - c0) : 0.f;
        float ddy = (y < Hn - 1) ? fabsf(pf[Wn] - c0) : 0.f;
        sf += 2.f * ddx + ddy;
        const float* pb = flowb + f3 + (size_t)j * DHW;
        float c1 = pb[0];
        float ddx2 = (x < Wn - 1) ? fabsf(pb[1] - c1) : 0.f;
        float ddy2 = (y < Hn - 1) ? fabsf(pb[Wn] - c1) : 0.f;
        sb2v += 2.f * ddx2 + ddy2;
    }
    float smoothv = 0.5f * (sf * (1.f / 3.f) + sb2v * (1.f / 3.f));

    float pv[13];
    pv[4] = l1 * nz; pv[5] = l1 * yz;
    pv[6] = l2 * nz; pv[7] = l2 * yz;
    pv[8] = nz; pv[9] = yz;
    pv[10] = cyc1; pv[11] = cyc2;
    pv[12] = smoothv;

#pragma unroll
    for (int i = 4; i < 13; i++) {
        float val = pv[i];
        for (int off = 32; off; off >>= 1) val += __shfl_down(val, off, 64);
        pv[i] = val;
    }
    __shared__ float sred[13][4];
    int lane = tid & 63, wid = tid >> 6;
    if (lane == 0) {
#pragma unroll
        for (int i = 4; i < 13; i++) sred[i][wid] = pv[i];
    }
    __syncthreads();
    if (tid >= 4 && tid < 13) {
        atomicAdd(&accum[tid], sred[tid][0] + sred[tid][1] + sred[tid][2] + sred[tid][3]);
    }
}

__global__ void finalize_kernel(const float* __restrict__ accum, float* __restrict__ out) {
    float hinge = accum[0] / (accum[1] + EPSF);
    float warp  = accum[2] / (accum[3] + EPSF);
    float l1b = 0.5f * (accum[4] / (accum[8] + EPSF) + accum[5] / (accum[9] + EPSF));
    float l2b = 0.5f * (accum[6] / (accum[8] + EPSF) + accum[7] / (accum[9] + EPSF));
    float n3 = 3.0f * (float)NVOX;
    float cyc = accum[10] / n3 + accum[11] / n3;
    float sm  = accum[12] / (float)NVOX;
    out[0] = hinge + cyc + l1b + l2b + warp + sm;
}

extern "C" void kernel_launch(void* const* d_in, const int* in_sizes, int n_in,
                              void* d_out, int out_size, void* d_ws, size_t ws_size,
                              hipStream_t stream) {
    const float* feat0  = (const float*)d_in[0];
    const float* feat1  = (const float*)d_in[1];
    const float* flow_g = (const float*)d_in[2];
    const float* mask_g = (const float*)d_in[3];
    const float* W1     = (const float*)d_in[4];
    const float* b1     = (const float*)d_in[5];
    const float* W2     = (const float*)d_in[6];
    const float* b2     = (const float*)d_in[7];

    float* out = (float*)d_out;
    float* accum = (float*)d_ws;
    float* flow_back = (float*)((char*)d_ws + 256);
    float* flow_forw = out + 1;

    hipMemsetAsync(d_ws, 0, 64, stream);

    dim3 block(256);
    corr_flow_kernel<<<dim3(NVOX / 256), block, 0, stream>>>(feat0, feat1, W1, b1, W2, b2,
                                                             flow_forw, flow_g, accum, 1);
    corr_flow_kernel<<<dim3(NVOX / 256), block, 0, stream>>>(feat1, feat0, W1, b1, W2, b2,
                                                             flow_back, nullptr, accum, 0);
    warp_feat_kernel<<<dim3(NVOX / 64), block, 0, stream>>>(feat0, feat1, flow_forw, accum);
    loss_rest_kernel<<<dim3(NVOX / 256), block, 0, stream>>>(flow_forw, flow_back,
                                                             flow_g, mask_g, accum);
    finalize_kernel<<<1, 1, 0, stream>>>(accum, out);
}

// Round 4
// 261.170 us; speedup vs baseline: 1.7870x; 1.7870x over previous
//
#include <hip/hip_runtime.h>
#include <math.h>

#define EPSF 1e-6f

constexpr int Bn = 2, Cn = 32, Dn = 64, Hn = 64, Wn = 64;
constexpr int HW  = Hn * Wn;          // 4096
constexpr int DHW = Dn * HW;          // 262144
constexpr int NVOX = Bn * DHW;        // 524288

// accum layout in ws:
// 0 hinge_num, 1 hinge_den, 2 warp_num, 3 warp_den,
// 4 l1_nz, 5 l1_yz, 6 l2_nz, 7 l2_yz, 8 nz_den, 9 yz_den,
// 10 cyc1, 11 cyc2, 12 smooth_sum

__device__ inline float sl1(float d) {
    float a = fabsf(d);
    return a < 1.f ? 0.5f * d * d : a - 0.5f;
}

// lane i <- lane i-1, lane 0 -> 0   (sample at x-1; x=0 edge zeroed = ref padding)
__device__ inline float dpp_left(float v) {
    int r = __builtin_amdgcn_update_dpp(0, __float_as_int(v), 0x138 /*wave_shr:1*/,
                                        0xF, 0xF, true);
    return __int_as_float(r);
}
// lane i <- lane i+1, lane 63 -> 0  (sample at x+1; x=63 edge zeroed)
__device__ inline float dpp_right(float v) {
    int r = __builtin_amdgcn_update_dpp(0, __float_as_int(v), 0x130 /*wave_shl:1*/,
                                        0xF, 0xF, true);
    return __int_as_float(r);
}

// Trilinear gather via 4 float2 x-pair loads instead of 8 scalar loads.
// pidx[k]: element index of the (x0,x0+1) pair within a DHW slab (clamped so
// the 8B load never leaves the slab); sel[k]: 1 if second corner is .y
// (x0 in [0,62]), else duplicated .x (clip cases — weight is 0 there).
struct PairGather {
    int   pidx[4];
    int   sel[4];
    float w0[4], w1[4];
};

__device__ inline void warp_pair_setup(float flx, float fly, float flz,
                                       int x, int y, int z,
                                       PairGather& pg, float& wsum) {
    float xs = (float)x + flx, ys = (float)y + fly, zs = (float)z + flz;
    float xf = floorf(xs), yf = floorf(ys), zf = floorf(zs);
    float fx = xs - xf, fy = ys - yf, fz = zs - zf;
    int xi = (int)xf, yi = (int)yf, zi = (int)zf;

    int x0c = min(max(xi, 0), Wn - 1);
    bool xv0 = (xi >= 0) && (xi < Wn);
    bool xv1 = (xi + 1 >= 0) && (xi + 1 < Wn);
    int sel = (xi >= 0 && xi < Wn - 1) ? 1 : 0;
    float wx0 = xv0 ? (1.f - fx) : 0.f;
    float wx1 = xv1 ? fx : 0.f;

    wsum = 0.f;
#pragma unroll
    for (int cz = 0; cz < 2; cz++) {
        int zz = zi + cz;
        bool zv = (zz >= 0) && (zz < Dn);
        int zc = min(max(zz, 0), Dn - 1);
        float wz = (cz ? fz : 1.f - fz) * (zv ? 1.f : 0.f);
#pragma unroll
        for (int cy = 0; cy < 2; cy++) {
            int yy = yi + cy;
            bool yv = (yy >= 0) && (yy < Hn);
            int yc = min(max(yy, 0), Hn - 1);
            float wy = (cy ? fy : 1.f - fy) * (yv ? 1.f : 0.f);
            int k = cz * 2 + cy;
            int sp = (zc * Hn + yc) * Wn + x0c;
            pg.pidx[k] = min(sp, DHW - 2);
            pg.sel[k] = sel;
            float wzy = wz * wy;
            pg.w0[k] = wzy * wx0;
            pg.w1[k] = wzy * wx1;
            wsum += pg.w0[k] + pg.w1[k];
        }
    }
}

__device__ inline float gather8(const float* __restrict__ slab, const PairGather& pg) {
    float g = 0.f;
#pragma unroll
    for (int k = 0; k < 4; k++) {
        float2 v = *reinterpret_cast<const float2*>(slab + pg.pidx[k]);
        float second = pg.sel[k] ? v.y : v.x;
        g = fmaf(v.x, pg.w0[k], g);
        g = fmaf(second, pg.w1[k], g);
    }
    return g;
}

// corr3d(f0,f1) -> relu -> l2norm(axis=1) -> W1/leaky -> W2 -> flow_out
// W1/b1/W2/b2 read directly from global with wave-uniform indices -> s_load.
__global__ __launch_bounds__(256)
void corr_flow_kernel(const float* __restrict__ f0, const float* __restrict__ f1,
                      const float* __restrict__ W1, const float* __restrict__ b1,
                      const float* __restrict__ W2, const float* __restrict__ b2,
                      float* __restrict__ flow_out,
                      const float* __restrict__ flow_g,
                      float* __restrict__ accum, int do_hinge) {
    int tid = threadIdx.x;
    int v = blockIdx.x * 256 + tid;
    int x = v & 63, y = (v >> 6) & 63, z = (v >> 12) & 63, b = v >> 18;

    const size_t cb = (size_t)b * Cn * DHW + (size_t)z * HW + y * Wn + x;
    const float* f0p = f0 + cb;
    const float* f1p = f1 + cb;

    // wave-uniform row validity (y,z constant across a wave)
    bool zv0 = z > 0, zv2 = z < Dn - 1;
    bool yv0 = y > 0, yv2 = y < Hn - 1;
    bool rvalid[9] = { zv0 && yv0, zv0, zv0 && yv2,
                       yv0,        true, yv2,
                       zv2 && yv0, zv2, zv2 && yv2 };
    const int rowoff[9] = { -HW - Wn, -HW, -HW + Wn,
                            -Wn,      0,   Wn,
                            HW - Wn,  HW,  HW + Wn };

    float acc[27];
#pragma unroll
    for (int i = 0; i < 27; i++) acc[i] = 0.f;
    float diff2 = 0.f;

    for (int c = 0; c < Cn; c++) {
        const float* p = f1p + (size_t)c * DHW;
        float a = f0p[(size_t)c * DHW];
        float rowv[9];
#pragma unroll
        for (int r = 0; r < 9; r++)
            rowv[r] = rvalid[r] ? p[rowoff[r]] : 0.f;
        float d = rowv[4] - a;
        diff2 = fmaf(d, d, diff2);
#pragma unroll
        for (int r = 0; r < 9; r++) {
            float c0 = rowv[r];
            float lf = dpp_left(c0);
            float rt = dpp_right(c0);
            acc[r * 3 + 0] = fmaf(a, lf, acc[r * 3 + 0]);
            acc[r * 3 + 1] = fmaf(a, c0, acc[r * 3 + 1]);
            acc[r * 3 + 2] = fmaf(a, rt, acc[r * 3 + 2]);
        }
    }

    // flow head: relu, normalize over 27 (eps OUTSIDE sqrt here)
    float ss = 0.f;
#pragma unroll
    for (int i = 0; i < 27; i++) {
        float r = acc[i] > 0.f ? acc[i] : 0.f;
        acc[i] = r;
        ss = fmaf(r, r, ss);
    }
    float inv = 1.0f / (sqrtf(ss) + EPSF);
#pragma unroll
    for (int i = 0; i < 27; i++) acc[i] *= inv;

    float fl0 = b2[0], fl1 = b2[1], fl2 = b2[2];
    for (int o = 0; o < 64; o++) {
        float h = b1[o];
#pragma unroll
        for (int k = 0; k < 27; k++) h = fmaf(W1[o * 27 + k], acc[k], h);
        h = h > 0.f ? h : 0.01f * h;
        fl0 = fmaf(W2[o], h, fl0);
        fl1 = fmaf(W2[64 + o], h, fl1);
        fl2 = fmaf(W2[128 + o], h, fl2);
    }
    size_t fbase = (size_t)b * 3 * DHW + (size_t)z * HW + y * Wn + x;
    flow_out[fbase] = fl0;
    flow_out[fbase + DHW] = fl1;
    flow_out[fbase + 2 * DHW] = fl2;

    if (do_hinge) {
        float ag = fabsf(flow_g[fbase]) + fabsf(flow_g[fbase + DHW]) + fabsf(flow_g[fbase + 2 * DHW]);
        float hmask = ag > 1.0f ? 1.f : 0.f;
        float hv = 0.2f - sqrtf(diff2 + EPSF);
        hv = hv > 0.f ? hv : 0.f;
        float v0 = hv * hmask, v1 = hmask;
        for (int off = 32; off; off >>= 1) {
            v0 += __shfl_down(v0, off, 64);
            v1 += __shfl_down(v1, off, 64);
        }
        __shared__ float s0[4], s1[4];
        int lane = tid & 63, wid = tid >> 6;
        if (lane == 0) { s0[wid] = v0; s1[wid] = v1; }
        __syncthreads();
        if (tid == 0) {
            atomicAdd(&accum[0], s0[0] + s0[1] + s0[2] + s0[3]);
            atomicAdd(&accum[1], s1[0] + s1[1] + s1[2] + s1[3]);
        }
    }
}

// merged per-voxel losses with float2 pair-gathers:
// feat warp (32ch), cycle x2, l1/l2 balanced, smoothness.
__global__ __launch_bounds__(256)
void loss_kernel(const float* __restrict__ feat0, const float* __restrict__ feat1,
                 const float* __restrict__ flowf, const float* __restrict__ flowb,
                 const float* __restrict__ flow_g, const float* __restrict__ mask_g,
                 float* __restrict__ accum) {
    int tid = threadIdx.x;
    int v = blockIdx.x * 256 + tid;
    int x = v & 63, y = (v >> 6) & 63, z = (v >> 12) & 63, b = v >> 18;

    size_t sp = (size_t)z * HW + y * Wn + x;
    size_t f3 = (size_t)b * 3 * DHW + sp;

    float ffx = flowf[f3], ffy = flowf[f3 + DHW], ffz = flowf[f3 + 2 * DHW];
    float fbx = flowb[f3], fby = flowb[f3 + DHW], fbz = flowb[f3 + 2 * DHW];
    float gx = flow_g[f3], gy = flow_g[f3 + DHW], gz = flow_g[f3 + 2 * DHW];
    float mg = mask_g[(size_t)b * DHW + sp];

    // forward warp pair-gather coefficients
    PairGather pgF; float wsumF;
    warp_pair_setup(ffx, ffy, ffz, x, y, z, pgF, wsumF);

    // feat1 backwarped by flow_forw, l2 diff to feat0
    const float* f1b = feat1 + (size_t)b * Cn * DHW;
    const float* f0b = feat0 + (size_t)b * Cn * DHW + sp;
    float s = 0.f;
#pragma unroll 4
    for (int c = 0; c < Cn; c++) {
        float g = gather8(f1b + (size_t)c * DHW, pgF);
        float d = g - f0b[(size_t)c * DHW];
        s = fmaf(d, d, s);
    }
    float vm = wsumF * wsumF;   // valid1*valid0 (both use flow_forw in ref)
    float warp_num = sqrtf(s + EPSF) * vm;
    float warp_den = vm;

    // cycle 1: fb_al = backwarp(flow_back, flow_forw)
    const float* fb_b = flowb + (size_t)b * 3 * DHW;
    float fbalx = gather8(fb_b, pgF);
    float fbaly = gather8(fb_b + DHW, pgF);
    float fbalz = gather8(fb_b + 2 * DHW, pgF);
    float cyc1 = sl1(ffx + fbalx) + sl1(ffy + fbaly) + sl1(ffz + fbalz);

    // cycle 2: ff_al = backwarp(flow_forw, flow_back)
    PairGather pgB; float wsumB;
    warp_pair_setup(fbx, fby, fbz, x, y, z, pgB, wsumB);
    const float* ff_b = flowf + (size_t)b * 3 * DHW;
    float ffalx = gather8(ff_b, pgB);
    float ffaly = gather8(ff_b + DHW, pgB);
    float ffalz = gather8(ff_b + 2 * DHW, pgB);
    float cyc2 = sl1(fbx + ffalx) + sl1(fby + ffaly) + sl1(fbz + ffalz);

    // l1/l2 balanced
    float dx0 = ffx - gx, dy0 = ffy - gy, dz0 = ffz - gz;
    float l1 = (sl1(dx0) + sl1(dy0) + sl1(dz0)) * (1.f / 3.f);
    float l2 = (dx0 * dx0 + dy0 * dy0 + dz0 * dz0) * (1.f / 3.f);
    float ag = fabsf(gx) + fabsf(gy) + fabsf(gz);
    float nz = (ag > 0.01f ? 1.f : 0.f) * mg;
    float yz = (1.f - nz) * mg;

    // smoothness: mean over channels of (2*dx + dy), dz unused (ref quirk)
    float sf = 0.f, sb2v = 0.f;
#pragma unroll
    for (int j = 0; j < 3; j++) {
        const float* pf = flowf + f3 + (size_t)j * DHW;
        float c0 = pf[0];
        float ddx = (x < Wn - 1) ? fabsf(pf[1] - c0) : 0.f;
        float ddy = (y < Hn - 1) ? fabsf(pf[Wn] - c0) : 0.f;
        sf += 2.f * ddx + ddy;
        const float* pb = flowb + f3 + (size_t)j * DHW;
        float c1 = pb[0];
        float ddx2 = (x < Wn - 1) ? fabsf(pb[1] - c1) : 0.f;
        float ddy2 = (y < Hn - 1) ? fabsf(pb[Wn] - c1) : 0.f;
        sb2v += 2.f * ddx2 + ddy2;
    }
    float smoothv = 0.5f * (sf * (1.f / 3.f) + sb2v * (1.f / 3.f));

    float pv[13];
    pv[2] = warp_num; pv[3] = warp_den;
    pv[4] = l1 * nz; pv[5] = l1 * yz;
    pv[6] = l2 * nz; pv[7] = l2 * yz;
    pv[8] = nz; pv[9] = yz;
    pv[10] = cyc1; pv[11] = cyc2;
    pv[12] = smoothv;

#pragma unroll
    for (int i = 2; i < 13; i++) {
        float val = pv[i];
        for (int off = 32; off; off >>= 1) val += __shfl_down(val, off, 64);
        pv[i] = val;
    }
    __shared__ float sred[13][4];
    int lane = tid & 63, wid = tid >> 6;
    if (lane == 0) {
#pragma unroll
        for (int i = 2; i < 13; i++) sred[i][wid] = pv[i];
    }
    __syncthreads();
    if (tid >= 2 && tid < 13) {
        atomicAdd(&accum[tid], sred[tid][0] + sred[tid][1] + sred[tid][2] + sred[tid][3]);
    }
}

__global__ void finalize_kernel(const float* __restrict__ accum, float* __restrict__ out) {
    float hinge = accum[0] / (accum[1] + EPSF);
    float warp  = accum[2] / (accum[3] + EPSF);
    float l1b = 0.5f * (accum[4] / (accum[8] + EPSF) + accum[5] / (accum[9] + EPSF));
    float l2b = 0.5f * (accum[6] / (accum[8] + EPSF) + accum[7] / (accum[9] + EPSF));
    float n3 = 3.0f * (float)NVOX;
    float cyc = accum[10] / n3 + accum[11] / n3;
    float sm  = accum[12] / (float)NVOX;
    out[0] = hinge + cyc + l1b + l2b + warp + sm;
}

extern "C" void kernel_launch(void* const* d_in, const int* in_sizes, int n_in,
                              void* d_out, int out_size, void* d_ws, size_t ws_size,
                              hipStream_t stream) {
    const float* feat0  = (const float*)d_in[0];
    const float* feat1  = (const float*)d_in[1];
    const float* flow_g = (const float*)d_in[2];
    const float* mask_g = (const float*)d_in[3];
    const float* W1     = (const float*)d_in[4];
    const float* b1     = (const float*)d_in[5];
    const float* W2     = (const float*)d_in[6];
    const float* b2     = (const float*)d_in[7];

    float* out = (float*)d_out;
    float* accum = (float*)d_ws;
    float* flow_back = (float*)((char*)d_ws + 256);
    float* flow_forw = out + 1;

    hipMemsetAsync(d_ws, 0, 64, stream);

    dim3 block(256);
    corr_flow_kernel<<<dim3(NVOX / 256), block, 0, stream>>>(feat0, feat1, W1, b1, W2, b2,
                                                             flow_forw, flow_g, accum, 1);
    corr_flow_kernel<<<dim3(NVOX / 256), block, 0, stream>>>(feat1, feat0, W1, b1, W2, b2,
                                                             flow_back, nullptr, accum, 0);
    loss_kernel<<<dim3(NVOX / 256), block, 0, stream>>>(feat0, feat1, flow_forw, flow_back,
                                                        flow_g, mask_g, accum);
    finalize_kernel<<<1, 1, 0, stream>>>(accum, out);
}